// Round 1
// baseline (1273.192 us; speedup 1.0000x reference)
//
#include <hip/hip_runtime.h>
#include <hip/hip_bf16.h>
#include <stdint.h>

#define S_LEN 2048
#define NQh   40
#define NKVh  8
#define HD    128
#define HIDd  5120
#define QKV_C 7208
#define QKV_P 7296   // padded to multiple of 128

typedef unsigned short u16;
typedef short bf16x8 __attribute__((ext_vector_type(8)));
typedef float f32x4  __attribute__((ext_vector_type(4)));
typedef u16   u16x4  __attribute__((ext_vector_type(4)));

typedef const __attribute__((address_space(1))) void* gas_ptr;
typedef __attribute__((address_space(3))) void*       las_ptr;

#define MFMA16(a, b, c) __builtin_amdgcn_mfma_f32_16x16x32_bf16(a, b, c, 0, 0, 0)

__device__ __forceinline__ u16 f2bf(float f) {
  union { float f; unsigned u; } v; v.f = f;
  return (u16)((v.u + 0x7fffu + ((v.u >> 16) & 1u)) >> 16);
}

__device__ __forceinline__ float wave_sum64(float x) {
#pragma unroll
  for (int m = 32; m > 0; m >>= 1) x += __shfl_xor(x, m, 64);
  return x;
}

// ---------------- Kernel 1: pre-norm RMSNorm -> bf16 ----------------
__global__ __launch_bounds__(256) void prenorm_kernel(
    const float* __restrict__ x, const float* __restrict__ w, u16* __restrict__ xn) {
  int row = blockIdx.x;
  const float4* xr = (const float4*)(x + (size_t)row * HIDd);
  const float4* wr = (const float4*)w;
  float4 vx[5];
  float ss = 0.f;
#pragma unroll
  for (int c = 0; c < 5; ++c) {
    int i = c * 256 + threadIdx.x;
    vx[c] = xr[i];
    ss += vx[c].x * vx[c].x + vx[c].y * vx[c].y + vx[c].z * vx[c].z + vx[c].w * vx[c].w;
  }
  ss = wave_sum64(ss);
  __shared__ float red[4];
  if ((threadIdx.x & 63) == 0) red[threadIdx.x >> 6] = ss;
  __syncthreads();
  float tot = red[0] + red[1] + red[2] + red[3];
  float n = rsqrtf(tot * (1.f / HIDd) + 1e-6f);
  u16x4* out = (u16x4*)(xn + (size_t)row * HIDd);
#pragma unroll
  for (int c = 0; c < 5; ++c) {
    int i = c * 256 + threadIdx.x;
    float4 vw = wr[i];
    u16x4 o;
    o.x = f2bf(vx[c].x * n * vw.x);
    o.y = f2bf(vx[c].y * n * vw.y);
    o.z = f2bf(vx[c].z * n * vw.z);
    o.w = f2bf(vx[c].w * n * vw.w);
    out[i] = o;
  }
}

// ---------------- Kernel 2: transpose + fp32->bf16 ----------------
// dst[z][c][r] = bf16(src[z][r][c]) for c < C, else 0.  grid: (Cpad/32, R/32, Z)
__global__ __launch_bounds__(256) void transpose_cvt(
    const float* __restrict__ src, u16* __restrict__ dst,
    int C, long ld_src, long ld_dst, long srcZ, long dstZ) {
  src += (long)blockIdx.z * srcZ;
  dst += (long)blockIdx.z * dstZ;
  __shared__ float t[32][33];
  int tx = threadIdx.x & 31, ty = threadIdx.x >> 5;
  int c0 = blockIdx.x * 32, r0 = blockIdx.y * 32;
#pragma unroll
  for (int i = 0; i < 32; i += 8) {
    int c = c0 + tx;
    t[ty + i][tx] = (c < C) ? src[(long)(r0 + ty + i) * ld_src + c] : 0.f;
  }
  __syncthreads();
#pragma unroll
  for (int i = 0; i < 32; i += 8) {
    int c = c0 + ty + i;
    dst[(long)c * ld_dst + (r0 + tx)] = f2bf(t[tx][ty + i]);
  }
}

// ---------------- Kernel 3: GEMM  C(MxN) = A(MxK bf16) * BT(NxK bf16)^T ----------------
// 128x128 tile, 4 waves (2x2), BK=64, global_load_lds width 16, m97 structure.
__global__ __launch_bounds__(256) void gemm_bt(
    const u16* __restrict__ A, const u16* __restrict__ BT, float* __restrict__ C,
    int M, int N, int K) {
  __shared__ __align__(16) u16 As[128 * 64];
  __shared__ __align__(16) u16 Bs[128 * 64];
  int w = threadIdx.x >> 6, l = threadIdx.x & 63;
  int wr = w >> 1, wc = w & 1;
  int g = l >> 4, q = l & 15;
  long mBase = (long)blockIdx.y * 128;
  long nBase = (long)blockIdx.x * 128;
  const u16* aTile = A + mBase * K;
  const u16* bTile = BT + nBase * K;
  f32x4 acc[4][4] = {};

  for (int k0 = 0; k0 < K; k0 += 64) {
#pragma unroll
    for (int i = 0; i < 4; ++i) {
      int s = (w * 4 + i) * 64 + l;          // 0..1023
      int row = s >> 3, seg = s & 7;
      __builtin_amdgcn_global_load_lds(
          (gas_ptr)(aTile + (long)row * K + k0 + seg * 8),
          (las_ptr)(As + (w * 4 + i) * 512), 16, 0, 0);
      __builtin_amdgcn_global_load_lds(
          (gas_ptr)(bTile + (long)row * K + k0 + seg * 8),
          (las_ptr)(Bs + (w * 4 + i) * 512), 16, 0, 0);
    }
    __syncthreads();
#pragma unroll
    for (int kk = 0; kk < 2; ++kk) {
      bf16x8 af[4], bfr[4];
#pragma unroll
      for (int i = 0; i < 4; ++i)
        af[i] = *(const bf16x8*)(As + (wr * 64 + i * 16 + q) * 64 + kk * 32 + g * 8);
#pragma unroll
      for (int j = 0; j < 4; ++j)
        bfr[j] = *(const bf16x8*)(Bs + (wc * 64 + j * 16 + q) * 64 + kk * 32 + g * 8);
#pragma unroll
      for (int i = 0; i < 4; ++i)
#pragma unroll
        for (int j = 0; j < 4; ++j)
          acc[i][j] = MFMA16(af[i], bfr[j], acc[i][j]);
    }
    __syncthreads();
  }
#pragma unroll
  for (int i = 0; i < 4; ++i)
#pragma unroll
    for (int j = 0; j < 4; ++j) {
      long mrow = mBase + wr * 64 + i * 16 + g * 4;
      long ncol = nBase + wc * 64 + j * 16 + q;
      float* cp = C + mrow * N + ncol;
#pragma unroll
      for (int r = 0; r < 4; ++r) cp[(long)r * N] = acc[i][j][r];
    }
}

// ---------------- Kernel 4: split + head-RMSNorm + RoPE + gate ----------------
__global__ __launch_bounds__(256) void split_kernel(
    const float* __restrict__ qkv, const float* __restrict__ cosb,
    const float* __restrict__ sinb, const float* __restrict__ wq,
    const float* __restrict__ wk, u16* __restrict__ qb, u16* __restrict__ kb,
    float* __restrict__ gate) {
  int s = blockIdx.x;
  int w = threadIdx.x >> 6, l = threadIdx.x & 63;
  const float* row = qkv + (size_t)s * QKV_P;
  float c0 = cosb[s * HD + l],      s0 = sinb[s * HD + l];
  float c1 = cosb[s * HD + 64 + l], s1 = sinb[s * HD + 64 + l];
  const float SCALE = 0.08838834764831845f;  // 1/sqrt(128), folded into q only
  for (int h = w; h < NQh; h += 4) {
    float x0 = row[h * HD + l], x1 = row[h * HD + 64 + l];
    float ss = wave_sum64(x0 * x0 + x1 * x1);
    float n = rsqrtf(ss * (1.f / HD) + 1e-6f);
    x0 *= n * wq[l]; x1 *= n * wq[64 + l];
    qb[((size_t)s * NQh + h) * HD + l]      = f2bf((x0 * c0 - x1 * s0) * SCALE);
    qb[((size_t)s * NQh + h) * HD + 64 + l] = f2bf((x1 * c1 + x0 * s1) * SCALE);
  }
  for (int h = w; h < NKVh; h += 4) {
    float x0 = row[NQh * HD + h * HD + l], x1 = row[NQh * HD + h * HD + 64 + l];
    float ss = wave_sum64(x0 * x0 + x1 * x1);
    float n = rsqrtf(ss * (1.f / HD) + 1e-6f);
    x0 *= n * wk[l]; x1 *= n * wk[64 + l];
    kb[((size_t)h * S_LEN + s) * HD + l]      = f2bf(x0 * c0 - x1 * s0);
    kb[((size_t)h * S_LEN + s) * HD + 64 + l] = f2bf(x1 * c1 + x0 * s1);
  }
  if (threadIdx.x < NQh) {
    float gx = row[(NQh + 2 * NKVh) * HD + threadIdx.x];
    gate[(size_t)s * NQh + threadIdx.x] = 1.f / (1.f + expf(-gx));
  }
}

// ---------------- Kernel 5: flash attention (swapped QK^T), GQA ----------------
// grid (S/64, NQ); 4 waves; wave w: 16 q-rows, loops kv in steps of 32.
__global__ __launch_bounds__(256) void attn_kernel(
    const u16* __restrict__ qb, const u16* __restrict__ kb,
    const u16* __restrict__ vT, const float* __restrict__ gate,
    u16* __restrict__ ob) {
  int h = blockIdx.y, hk = h / 5;
  int w = threadIdx.x >> 6, l = threadIdx.x & 63;
  int g = l >> 4, q = l & 15;
  int s0 = blockIdx.x * 64 + w * 16;
  __shared__ __align__(16) u16 Plds[4][16][40];  // per-wave private [q][kv(pad)]

  bf16x8 qf[4];
#pragma unroll
  for (int kk = 0; kk < 4; ++kk)
    qf[kk] = *(const bf16x8*)(qb + ((size_t)(s0 + q) * NQh + h) * HD + kk * 32 + g * 8);

  const u16* Kh = kb + (size_t)hk * S_LEN * HD;   // (s, d)
  const u16* Vh = vT + (size_t)hk * HD * S_LEN;   // (d, s)
  f32x4 oacc[8] = {};
  float m_run = -1e30f, l_run = 0.f;
  const float L2E = 1.4426950408889634f;

  for (int k0 = 0; k0 < S_LEN; k0 += 32) {
    f32x4 sacc[2] = {};
#pragma unroll
    for (int kk = 0; kk < 4; ++kk) {
      bf16x8 ka0 = *(const bf16x8*)(Kh + (size_t)(k0 + q) * HD + kk * 32 + g * 8);
      bf16x8 ka1 = *(const bf16x8*)(Kh + (size_t)(k0 + 16 + q) * HD + kk * 32 + g * 8);
      sacc[0] = MFMA16(ka0, qf[kk], sacc[0]);   // S^T[key][q]
      sacc[1] = MFMA16(ka1, qf[kk], sacc[1]);
    }
    float mx = sacc[0][0];
#pragma unroll
    for (int r = 1; r < 4; ++r) mx = fmaxf(mx, sacc[0][r]);
#pragma unroll
    for (int r = 0; r < 4; ++r) mx = fmaxf(mx, sacc[1][r]);
    mx = fmaxf(mx, __shfl_xor(mx, 16, 64));
    mx = fmaxf(mx, __shfl_xor(mx, 32, 64));
    float mnew = fmaxf(m_run, mx);
    float pv[8];
    float rowsum = 0.f;
#pragma unroll
    for (int t = 0; t < 2; ++t)
#pragma unroll
      for (int r = 0; r < 4; ++r) {
        float p = exp2f((sacc[t][r] - mnew) * L2E);
        pv[t * 4 + r] = p;
        rowsum += p;
      }
    rowsum += __shfl_xor(rowsum, 16, 64);
    rowsum += __shfl_xor(rowsum, 32, 64);
    if (__any(mx > m_run)) {                 // exact: corr==1 for lanes not raised
      float corr = exp2f((m_run - mnew) * L2E);
#pragma unroll
      for (int dt = 0; dt < 8; ++dt)
#pragma unroll
        for (int r = 0; r < 4; ++r) oacc[dt][r] *= corr;
      l_run *= corr;
    }
    l_run += rowsum;
    m_run = mnew;
    // P^T (acc layout) -> P (A-of-PV layout) via per-wave LDS round trip
    u16x4 p0, p1;
    p0.x = f2bf(pv[0]); p0.y = f2bf(pv[1]); p0.z = f2bf(pv[2]); p0.w = f2bf(pv[3]);
    p1.x = f2bf(pv[4]); p1.y = f2bf(pv[5]); p1.z = f2bf(pv[6]); p1.w = f2bf(pv[7]);
    *(u16x4*)&Plds[w][q][g * 4]      = p0;   // kv 4g..4g+3
    *(u16x4*)&Plds[w][q][16 + g * 4] = p1;   // kv 16+4g..
    bf16x8 pf = *(const bf16x8*)&Plds[w][q][g * 8];  // P[q][8g..8g+7]
#pragma unroll
    for (int dt = 0; dt < 8; ++dt) {
      bf16x8 va = *(const bf16x8*)(Vh + (size_t)(dt * 16 + q) * S_LEN + k0 + g * 8);
      oacc[dt] = MFMA16(va, pf, oacc[dt]);   // O^T[d][q]
    }
  }
  float gt = gate[(size_t)(s0 + q) * NQh + h] / l_run;
#pragma unroll
  for (int dt = 0; dt < 8; ++dt) {
    u16x4 o;
    o.x = f2bf(oacc[dt][0] * gt);
    o.y = f2bf(oacc[dt][1] * gt);
    o.z = f2bf(oacc[dt][2] * gt);
    o.w = f2bf(oacc[dt][3] * gt);
    *(u16x4*)(ob + ((size_t)(s0 + q) * NQh + h) * HD + dt * 16 + g * 4) = o;
  }
}

// ---------------- host ----------------
extern "C" void kernel_launch(void* const* d_in, const int* in_sizes, int n_in,
                              void* d_out, int out_size, void* d_ws, size_t ws_size,
                              hipStream_t stream) {
  const float* x     = (const float*)d_in[0];
  const float* rc    = (const float*)d_in[1];
  const float* rs    = (const float*)d_in[2];
  const float* wpre  = (const float*)d_in[3];
  const float* wqkv  = (const float*)d_in[4];
  const float* wqn   = (const float*)d_in[5];
  const float* wkn   = (const float*)d_in[6];
  const float* wproj = (const float*)d_in[7];
  float* out = (float*)d_out;

  char* ws = (char*)d_ws;
  size_t off = 0;
  auto alloc = [&](size_t bytes) -> void* {
    void* p = ws + off;
    off += (bytes + 255) & ~(size_t)255;
    return p;
  };
  u16*   xn     = (u16*)  alloc((size_t)S_LEN * HIDd * 2);
  u16*   wqkvT  = (u16*)  alloc((size_t)QKV_P * HIDd * 2);
  u16*   wprojT = (u16*)  alloc((size_t)HIDd * HIDd * 2);
  float* qkv    = (float*)alloc((size_t)S_LEN * QKV_P * 4);
  u16*   qb     = (u16*)  alloc((size_t)S_LEN * NQh * HD * 2);
  u16*   kb     = (u16*)  alloc((size_t)NKVh * S_LEN * HD * 2);
  u16*   vT     = (u16*)  alloc((size_t)NKVh * HD * S_LEN * 2);
  float* gate   = (float*)alloc((size_t)S_LEN * NQh * 4);
  u16*   ob     = (u16*)  alloc((size_t)S_LEN * NQh * HD * 2);
  if (off > ws_size) return;  // workspace insufficient -> visible clean failure

  prenorm_kernel<<<S_LEN, 256, 0, stream>>>(x, wpre, xn);
  transpose_cvt<<<dim3(QKV_P / 32, HIDd / 32, 1), 256, 0, stream>>>(
      wqkv, wqkvT, QKV_C, (long)QKV_C, (long)HIDd, 0, 0);
  transpose_cvt<<<dim3(HIDd / 32, HIDd / 32, 1), 256, 0, stream>>>(
      wproj, wprojT, HIDd, (long)HIDd, (long)HIDd, 0, 0);
  gemm_bt<<<dim3(QKV_P / 128, S_LEN / 128), 256, 0, stream>>>(
      xn, wqkvT, qkv, S_LEN, QKV_P, HIDd);
  split_kernel<<<S_LEN, 256, 0, stream>>>(qkv, rc, rs, wqn, wkn, qb, kb, gate);
  transpose_cvt<<<dim3(HD / 32, S_LEN / 32, NKVh), 256, 0, stream>>>(
      qkv + (NQh + NKVh) * HD, vT, HD, (long)QKV_P, (long)S_LEN,
      128, (long)HD * S_LEN);
  attn_kernel<<<dim3(S_LEN / 64, NQh), 256, 0, stream>>>(qb, kb, vT, gate, ob);
  gemm_bt<<<dim3(HIDd / 128, S_LEN / 128), 256, 0, stream>>>(
      ob, wprojT, out, S_LEN, HIDd, HIDd);
}

// Round 2
// 1056.076 us; speedup vs baseline: 1.2056x; 1.2056x over previous
//
#include <hip/hip_runtime.h>
#include <hip/hip_bf16.h>
#include <stdint.h>

#define S_LEN 2048
#define NQh   40
#define NKVh  8
#define HD    128
#define HIDd  5120
#define QKV_C 7208
#define QKV_P 7296   // padded to multiple of 128

typedef unsigned short u16;
typedef short bf16x8 __attribute__((ext_vector_type(8)));
typedef float f32x4  __attribute__((ext_vector_type(4)));
typedef u16   u16x4  __attribute__((ext_vector_type(4)));

typedef const __attribute__((address_space(1))) void* gas_ptr;
typedef __attribute__((address_space(3))) void*       las_ptr;

#define MFMA16(a, b, c) __builtin_amdgcn_mfma_f32_16x16x32_bf16(a, b, c, 0, 0, 0)

__device__ __forceinline__ u16 f2bf(float f) {
  union { float f; unsigned u; } v; v.f = f;
  return (u16)((v.u + 0x7fffu + ((v.u >> 16) & 1u)) >> 16);
}

__device__ __forceinline__ float wave_sum64(float x) {
#pragma unroll
  for (int m = 32; m > 0; m >>= 1) x += __shfl_xor(x, m, 64);
  return x;
}

// ---------------- Kernel 1: pre-norm RMSNorm -> bf16 ----------------
__global__ __launch_bounds__(256) void prenorm_kernel(
    const float* __restrict__ x, const float* __restrict__ w, u16* __restrict__ xn) {
  int row = blockIdx.x;
  const float4* xr = (const float4*)(x + (size_t)row * HIDd);
  const float4* wr = (const float4*)w;
  float4 vx[5];
  float ss = 0.f;
#pragma unroll
  for (int c = 0; c < 5; ++c) {
    int i = c * 256 + threadIdx.x;
    vx[c] = xr[i];
    ss += vx[c].x * vx[c].x + vx[c].y * vx[c].y + vx[c].z * vx[c].z + vx[c].w * vx[c].w;
  }
  ss = wave_sum64(ss);
  __shared__ float red[4];
  if ((threadIdx.x & 63) == 0) red[threadIdx.x >> 6] = ss;
  __syncthreads();
  float tot = red[0] + red[1] + red[2] + red[3];
  float n = rsqrtf(tot * (1.f / HIDd) + 1e-6f);
  u16x4* out = (u16x4*)(xn + (size_t)row * HIDd);
#pragma unroll
  for (int c = 0; c < 5; ++c) {
    int i = c * 256 + threadIdx.x;
    float4 vw = wr[i];
    u16x4 o;
    o.x = f2bf(vx[c].x * n * vw.x);
    o.y = f2bf(vx[c].y * n * vw.y);
    o.z = f2bf(vx[c].z * n * vw.z);
    o.w = f2bf(vx[c].w * n * vw.w);
    out[i] = o;
  }
}

// ---------------- Kernel 2: transpose + fp32->bf16 ----------------
// dst[z][c][r] = bf16(src[z][r][c]) for c < C, else 0.  grid: (Cpad/32, R/32, Z)
__global__ __launch_bounds__(256) void transpose_cvt(
    const float* __restrict__ src, u16* __restrict__ dst,
    int C, long ld_src, long ld_dst, long srcZ, long dstZ) {
  src += (long)blockIdx.z * srcZ;
  dst += (long)blockIdx.z * dstZ;
  __shared__ float t[32][33];
  int tx = threadIdx.x & 31, ty = threadIdx.x >> 5;
  int c0 = blockIdx.x * 32, r0 = blockIdx.y * 32;
#pragma unroll
  for (int i = 0; i < 32; i += 8) {
    int c = c0 + tx;
    t[ty + i][tx] = (c < C) ? src[(long)(r0 + ty + i) * ld_src + c] : 0.f;
  }
  __syncthreads();
#pragma unroll
  for (int i = 0; i < 32; i += 8) {
    int c = c0 + ty + i;
    dst[(long)c * ld_dst + (r0 + tx)] = f2bf(t[tx][ty + i]);
  }
}

// ---------------- Kernel 3: GEMM  C(MxN) = A(MxK bf16) * BT(NxK bf16)^T ----------------
// 128x128 tile, 4 waves (2x2), BK=64, global_load_lds width 16, m97 structure.
__global__ __launch_bounds__(256) void gemm_bt(
    const u16* __restrict__ A, const u16* __restrict__ BT, float* __restrict__ C,
    int M, int N, int K) {
  __shared__ __align__(16) u16 As[128 * 64];
  __shared__ __align__(16) u16 Bs[128 * 64];
  int w = threadIdx.x >> 6, l = threadIdx.x & 63;
  int wr = w >> 1, wc = w & 1;
  int g = l >> 4, q = l & 15;
  long mBase = (long)blockIdx.y * 128;
  long nBase = (long)blockIdx.x * 128;
  const u16* aTile = A + mBase * K;
  const u16* bTile = BT + nBase * K;
  f32x4 acc[4][4] = {};

  for (int k0 = 0; k0 < K; k0 += 64) {
#pragma unroll
    for (int i = 0; i < 4; ++i) {
      int s = (w * 4 + i) * 64 + l;          // 0..1023
      int row = s >> 3, seg = s & 7;
      __builtin_amdgcn_global_load_lds(
          (gas_ptr)(aTile + (long)row * K + k0 + seg * 8),
          (las_ptr)(As + (w * 4 + i) * 512), 16, 0, 0);
      __builtin_amdgcn_global_load_lds(
          (gas_ptr)(bTile + (long)row * K + k0 + seg * 8),
          (las_ptr)(Bs + (w * 4 + i) * 512), 16, 0, 0);
    }
    __syncthreads();
#pragma unroll
    for (int kk = 0; kk < 2; ++kk) {
      bf16x8 af[4], bfr[4];
#pragma unroll
      for (int i = 0; i < 4; ++i)
        af[i] = *(const bf16x8*)(As + (wr * 64 + i * 16 + q) * 64 + kk * 32 + g * 8);
#pragma unroll
      for (int j = 0; j < 4; ++j)
        bfr[j] = *(const bf16x8*)(Bs + (wc * 64 + j * 16 + q) * 64 + kk * 32 + g * 8);
#pragma unroll
      for (int i = 0; i < 4; ++i)
#pragma unroll
        for (int j = 0; j < 4; ++j)
          acc[i][j] = MFMA16(af[i], bfr[j], acc[i][j]);
    }
    __syncthreads();
  }
#pragma unroll
  for (int i = 0; i < 4; ++i)
#pragma unroll
    for (int j = 0; j < 4; ++j) {
      long mrow = mBase + wr * 64 + i * 16 + g * 4;
      long ncol = nBase + wc * 64 + j * 16 + q;
      float* cp = C + mrow * N + ncol;
#pragma unroll
      for (int r = 0; r < 4; ++r) cp[(long)r * N] = acc[i][j][r];
    }
}

// ---------------- Kernel 4: split + head-RMSNorm + RoPE + gate ----------------
__global__ __launch_bounds__(256) void split_kernel(
    const float* __restrict__ qkv, const float* __restrict__ cosb,
    const float* __restrict__ sinb, const float* __restrict__ wq,
    const float* __restrict__ wk, u16* __restrict__ qb, u16* __restrict__ kb,
    float* __restrict__ gate) {
  int s = blockIdx.x;
  int w = threadIdx.x >> 6, l = threadIdx.x & 63;
  const float* row = qkv + (size_t)s * QKV_P;
  float c0 = cosb[s * HD + l],      s0 = sinb[s * HD + l];
  float c1 = cosb[s * HD + 64 + l], s1 = sinb[s * HD + 64 + l];
  const float SCALE = 0.08838834764831845f;  // 1/sqrt(128), folded into q only
  for (int h = w; h < NQh; h += 4) {
    float x0 = row[h * HD + l], x1 = row[h * HD + 64 + l];
    float ss = wave_sum64(x0 * x0 + x1 * x1);
    float n = rsqrtf(ss * (1.f / HD) + 1e-6f);
    x0 *= n * wq[l]; x1 *= n * wq[64 + l];
    qb[((size_t)s * NQh + h) * HD + l]      = f2bf((x0 * c0 - x1 * s0) * SCALE);
    qb[((size_t)s * NQh + h) * HD + 64 + l] = f2bf((x1 * c1 + x0 * s1) * SCALE);
  }
  for (int h = w; h < NKVh; h += 4) {
    float x0 = row[NQh * HD + h * HD + l], x1 = row[NQh * HD + h * HD + 64 + l];
    float ss = wave_sum64(x0 * x0 + x1 * x1);
    float n = rsqrtf(ss * (1.f / HD) + 1e-6f);
    x0 *= n * wk[l]; x1 *= n * wk[64 + l];
    kb[((size_t)h * S_LEN + s) * HD + l]      = f2bf(x0 * c0 - x1 * s0);
    kb[((size_t)h * S_LEN + s) * HD + 64 + l] = f2bf(x1 * c1 + x0 * s1);
  }
  if (threadIdx.x < NQh) {
    float gx = row[(NQh + 2 * NKVh) * HD + threadIdx.x];
    gate[(size_t)s * NQh + threadIdx.x] = 1.f / (1.f + expf(-gx));
  }
}

// ---------------- Kernel 5: flash attention v2 (swapped QK^T), GQA ----------------
// grid (S/128, NQ); 4 waves; wave w: 32 q-rows (2 subtiles), kv in steps of 64.
__global__ __launch_bounds__(256, 2) void attn_kernel(
    const u16* __restrict__ qb, const u16* __restrict__ kb,
    const u16* __restrict__ vT, const float* __restrict__ gate,
    u16* __restrict__ ob) {
  int h = blockIdx.y, hk = h / 5;
  int w = threadIdx.x >> 6, l = threadIdx.x & 63;
  int g = l >> 4, q = l & 15;
  int s0 = blockIdx.x * 128 + w * 32;
  __shared__ __align__(16) u16 Plds[4][2][16][72];  // per-wave private [p][q][kv pad]

  bf16x8 qf[2][4];
#pragma unroll
  for (int p = 0; p < 2; ++p)
#pragma unroll
    for (int kk = 0; kk < 4; ++kk)
      qf[p][kk] = *(const bf16x8*)(qb + ((size_t)(s0 + p * 16 + q) * NQh + h) * HD + kk * 32 + g * 8);

  const u16* Kh = kb + (size_t)hk * S_LEN * HD;   // (s, d)
  const u16* Vh = vT + (size_t)hk * HD * S_LEN;   // (d, s)
  f32x4 oacc[8][2] = {};
  float m_run[2] = {-1e30f, -1e30f};
  float l_run[2] = {0.f, 0.f};
  const float L2E = 1.4426950408889634f;

  for (int k0 = 0; k0 < S_LEN; k0 += 64) {
    // ---- QK^T: S^T[64 kv][32 q] ----
    f32x4 sacc[4][2] = {};
#pragma unroll
    for (int kk = 0; kk < 4; ++kk) {
      bf16x8 ka[4];
#pragma unroll
      for (int kt = 0; kt < 4; ++kt)
        ka[kt] = *(const bf16x8*)(Kh + (size_t)(k0 + kt * 16 + q) * HD + kk * 32 + g * 8);
      __builtin_amdgcn_s_setprio(1);
#pragma unroll
      for (int kt = 0; kt < 4; ++kt) {
        sacc[kt][0] = MFMA16(ka[kt], qf[0][kk], sacc[kt][0]);
        sacc[kt][1] = MFMA16(ka[kt], qf[1][kk], sacc[kt][1]);
      }
      __builtin_amdgcn_s_setprio(0);
    }
    // ---- online softmax (per q-subtile) ----
#pragma unroll
    for (int p = 0; p < 2; ++p) {
      float mx = sacc[0][p][0];
#pragma unroll
      for (int kt = 0; kt < 4; ++kt)
#pragma unroll
        for (int r = 0; r < 4; ++r)
          if (kt | r) mx = fmaxf(mx, sacc[kt][p][r]);
      mx = fmaxf(mx, __shfl_xor(mx, 16, 64));
      mx = fmaxf(mx, __shfl_xor(mx, 32, 64));
      float mnew = fmaxf(m_run[p], mx);
      float rs = 0.f;
#pragma unroll
      for (int kt = 0; kt < 4; ++kt)
#pragma unroll
        for (int r = 0; r < 4; ++r) {
          float pe = exp2f((sacc[kt][p][r] - mnew) * L2E);
          sacc[kt][p][r] = pe;
          rs += pe;
        }
      rs += __shfl_xor(rs, 16, 64);
      rs += __shfl_xor(rs, 32, 64);
      if (__any(mx > m_run[p])) {            // exact: corr==1 for lanes not raised
        float corr = exp2f((m_run[p] - mnew) * L2E);
#pragma unroll
        for (int dt = 0; dt < 8; ++dt) oacc[dt][p] *= corr;
        l_run[p] *= corr;
      }
      l_run[p] += rs;
      m_run[p] = mnew;
      // pack P (bf16) to per-wave LDS: Plds[w][p][q][kv]
#pragma unroll
      for (int kt = 0; kt < 4; ++kt) {
        u16x4 pk;
#pragma unroll
        for (int r = 0; r < 4; ++r) pk[r] = f2bf(sacc[kt][p][r]);
        *(u16x4*)&Plds[w][p][q][kt * 16 + g * 4] = pk;
      }
    }
    // ---- PV: O^T[128 d][32 q] += V^T tile * P ----
#pragma unroll
    for (int kk2 = 0; kk2 < 2; ++kk2) {
      bf16x8 pf0 = *(const bf16x8*)&Plds[w][0][q][kk2 * 32 + g * 8];
      bf16x8 pf1 = *(const bf16x8*)&Plds[w][1][q][kk2 * 32 + g * 8];
#pragma unroll
      for (int dt = 0; dt < 8; ++dt) {
        bf16x8 va = *(const bf16x8*)(Vh + (size_t)(dt * 16 + q) * S_LEN + k0 + kk2 * 32 + g * 8);
        __builtin_amdgcn_s_setprio(1);
        oacc[dt][0] = MFMA16(va, pf0, oacc[dt][0]);
        oacc[dt][1] = MFMA16(va, pf1, oacc[dt][1]);
        __builtin_amdgcn_s_setprio(0);
      }
    }
  }
#pragma unroll
  for (int p = 0; p < 2; ++p) {
    float gt = gate[(size_t)(s0 + p * 16 + q) * NQh + h] / l_run[p];
#pragma unroll
    for (int dt = 0; dt < 8; ++dt) {
      u16x4 o;
#pragma unroll
      for (int r = 0; r < 4; ++r) o[r] = f2bf(oacc[dt][p][r] * gt);
      *(u16x4*)(ob + ((size_t)(s0 + p * 16 + q) * NQh + h) * HD + dt * 16 + g * 4) = o;
    }
  }
}

// ---------------- host ----------------
extern "C" void kernel_launch(void* const* d_in, const int* in_sizes, int n_in,
                              void* d_out, int out_size, void* d_ws, size_t ws_size,
                              hipStream_t stream) {
  const float* x     = (const float*)d_in[0];
  const float* rc    = (const float*)d_in[1];
  const float* rs    = (const float*)d_in[2];
  const float* wpre  = (const float*)d_in[3];
  const float* wqkv  = (const float*)d_in[4];
  const float* wqn   = (const float*)d_in[5];
  const float* wkn   = (const float*)d_in[6];
  const float* wproj = (const float*)d_in[7];
  float* out = (float*)d_out;

  char* ws = (char*)d_ws;
  size_t off = 0;
  auto alloc = [&](size_t bytes) -> void* {
    void* p = ws + off;
    off += (bytes + 255) & ~(size_t)255;
    return p;
  };
  u16*   xn     = (u16*)  alloc((size_t)S_LEN * HIDd * 2);
  u16*   wqkvT  = (u16*)  alloc((size_t)QKV_P * HIDd * 2);
  u16*   wprojT = (u16*)  alloc((size_t)HIDd * HIDd * 2);
  float* qkv    = (float*)alloc((size_t)S_LEN * QKV_P * 4);
  u16*   qb     = (u16*)  alloc((size_t)S_LEN * NQh * HD * 2);
  u16*   kb     = (u16*)  alloc((size_t)NKVh * S_LEN * HD * 2);
  u16*   vT     = (u16*)  alloc((size_t)NKVh * HD * S_LEN * 2);
  float* gate   = (float*)alloc((size_t)S_LEN * NQh * 4);
  u16*   ob     = (u16*)  alloc((size_t)S_LEN * NQh * HD * 2);
  if (off > ws_size) return;  // workspace insufficient -> visible clean failure

  prenorm_kernel<<<S_LEN, 256, 0, stream>>>(x, wpre, xn);
  transpose_cvt<<<dim3(QKV_P / 32, HIDd / 32, 1), 256, 0, stream>>>(
      wqkv, wqkvT, QKV_C, (long)QKV_C, (long)HIDd, 0, 0);
  transpose_cvt<<<dim3(HIDd / 32, HIDd / 32, 1), 256, 0, stream>>>(
      wproj, wprojT, HIDd, (long)HIDd, (long)HIDd, 0, 0);
  gemm_bt<<<dim3(QKV_P / 128, S_LEN / 128), 256, 0, stream>>>(
      xn, wqkvT, qkv, S_LEN, QKV_P, HIDd);
  split_kernel<<<S_LEN, 256, 0, stream>>>(qkv, rc, rs, wqn, wkn, qb, kb, gate);
  transpose_cvt<<<dim3(HD / 32, S_LEN / 32, NKVh), 256, 0, stream>>>(
      qkv + (NQh + NKVh) * HD, vT, HD, (long)QKV_P, (long)S_LEN,
      128, (long)HD * S_LEN);
  attn_kernel<<<dim3(S_LEN / 128, NQh), 256, 0, stream>>>(qb, kb, vT, gate, ob);
  gemm_bt<<<dim3(HIDd / 128, S_LEN / 128), 256, 0, stream>>>(
      ob, wprojT, out, S_LEN, HIDd, HIDd);
}

// Round 3
// 944.040 us; speedup vs baseline: 1.3487x; 1.1187x over previous
//
#include <hip/hip_runtime.h>
#include <hip/hip_bf16.h>
#include <stdint.h>

#define S_LEN 2048
#define NQh   40
#define NKVh  8
#define HD    128
#define HIDd  5120
#define QKV_C 7208
#define QKV_P 7296   // padded to multiple of 128

typedef unsigned short u16;
typedef short bf16x8 __attribute__((ext_vector_type(8)));
typedef float f32x4  __attribute__((ext_vector_type(4)));
typedef u16   u16x4  __attribute__((ext_vector_type(4)));

typedef const __attribute__((address_space(1))) void* gas_ptr;
typedef __attribute__((address_space(3))) void*       las_ptr;

#define MFMA16(a, b, c) __builtin_amdgcn_mfma_f32_16x16x32_bf16(a, b, c, 0, 0, 0)

__device__ __forceinline__ u16 f2bf(float f) {
  union { float f; unsigned u; } v; v.f = f;
  return (u16)((v.u + 0x7fffu + ((v.u >> 16) & 1u)) >> 16);
}

__device__ __forceinline__ float wave_sum64(float x) {
#pragma unroll
  for (int m = 32; m > 0; m >>= 1) x += __shfl_xor(x, m, 64);
  return x;
}

// ---------------- Kernel 1: pre-norm RMSNorm -> bf16 ----------------
__global__ __launch_bounds__(256) void prenorm_kernel(
    const float* __restrict__ x, const float* __restrict__ w, u16* __restrict__ xn) {
  int row = blockIdx.x;
  const float4* xr = (const float4*)(x + (size_t)row * HIDd);
  const float4* wr = (const float4*)w;
  float4 vx[5];
  float ss = 0.f;
#pragma unroll
  for (int c = 0; c < 5; ++c) {
    int i = c * 256 + threadIdx.x;
    vx[c] = xr[i];
    ss += vx[c].x * vx[c].x + vx[c].y * vx[c].y + vx[c].z * vx[c].z + vx[c].w * vx[c].w;
  }
  ss = wave_sum64(ss);
  __shared__ float red[4];
  if ((threadIdx.x & 63) == 0) red[threadIdx.x >> 6] = ss;
  __syncthreads();
  float tot = red[0] + red[1] + red[2] + red[3];
  float n = rsqrtf(tot * (1.f / HIDd) + 1e-6f);
  u16x4* out = (u16x4*)(xn + (size_t)row * HIDd);
#pragma unroll
  for (int c = 0; c < 5; ++c) {
    int i = c * 256 + threadIdx.x;
    float4 vw = wr[i];
    u16x4 o;
    o.x = f2bf(vx[c].x * n * vw.x);
    o.y = f2bf(vx[c].y * n * vw.y);
    o.z = f2bf(vx[c].z * n * vw.z);
    o.w = f2bf(vx[c].w * n * vw.w);
    out[i] = o;
  }
}

// ---------------- Kernel 2: transpose + fp32->bf16 ----------------
// dst[z][c][r] = bf16(src[z][r][c]) for c < C, else 0.  grid: (Cpad/32, R/32, Z)
__global__ __launch_bounds__(256) void transpose_cvt(
    const float* __restrict__ src, u16* __restrict__ dst,
    int C, long ld_src, long ld_dst, long srcZ, long dstZ) {
  src += (long)blockIdx.z * srcZ;
  dst += (long)blockIdx.z * dstZ;
  __shared__ float t[32][33];
  int tx = threadIdx.x & 31, ty = threadIdx.x >> 5;
  int c0 = blockIdx.x * 32, r0 = blockIdx.y * 32;
#pragma unroll
  for (int i = 0; i < 32; i += 8) {
    int c = c0 + tx;
    t[ty + i][tx] = (c < C) ? src[(long)(r0 + ty + i) * ld_src + c] : 0.f;
  }
  __syncthreads();
#pragma unroll
  for (int i = 0; i < 32; i += 8) {
    int c = c0 + ty + i;
    dst[(long)c * ld_dst + (r0 + tx)] = f2bf(t[tx][ty + i]);
  }
}

// ---------------- Kernel 3: GEMM  C(MxN) = A(MxK bf16) * BT(NxK bf16)^T ----------------
// 128x128 tile, 4 waves (2x2), BK=64, global_load_lds width 16, m97 structure.
// XCD-aware bijective swizzle (grids here are multiples of 8).
__global__ __launch_bounds__(256) void gemm_bt(
    const u16* __restrict__ A, const u16* __restrict__ BT, float* __restrict__ C,
    int M, int N, int K) {
  __shared__ __align__(16) u16 As[128 * 64];
  __shared__ __align__(16) u16 Bs[128 * 64];
  int w = threadIdx.x >> 6, l = threadIdx.x & 63;
  int wr = w >> 1, wc = w & 1;
  int g = l >> 4, q = l & 15;
  // XCD swizzle: nwg % 8 == 0 for both our grids (912, 640)
  int nwg = gridDim.x * gridDim.y;
  int wgid = blockIdx.y * gridDim.x + blockIdx.x;
  int swz = (wgid & 7) * (nwg >> 3) + (wgid >> 3);
  int bx = swz % gridDim.x, by = swz / gridDim.x;
  long mBase = (long)by * 128;
  long nBase = (long)bx * 128;
  const u16* aTile = A + mBase * K;
  const u16* bTile = BT + nBase * K;
  f32x4 acc[4][4] = {};

  for (int k0 = 0; k0 < K; k0 += 64) {
#pragma unroll
    for (int i = 0; i < 4; ++i) {
      int s = (w * 4 + i) * 64 + l;          // 0..1023
      int row = s >> 3, seg = s & 7;
      __builtin_amdgcn_global_load_lds(
          (gas_ptr)(aTile + (long)row * K + k0 + seg * 8),
          (las_ptr)(As + (w * 4 + i) * 512), 16, 0, 0);
      __builtin_amdgcn_global_load_lds(
          (gas_ptr)(bTile + (long)row * K + k0 + seg * 8),
          (las_ptr)(Bs + (w * 4 + i) * 512), 16, 0, 0);
    }
    __syncthreads();
#pragma unroll
    for (int kk = 0; kk < 2; ++kk) {
      bf16x8 af[4], bfr[4];
#pragma unroll
      for (int i = 0; i < 4; ++i)
        af[i] = *(const bf16x8*)(As + (wr * 64 + i * 16 + q) * 64 + kk * 32 + g * 8);
#pragma unroll
      for (int j = 0; j < 4; ++j)
        bfr[j] = *(const bf16x8*)(Bs + (wc * 64 + j * 16 + q) * 64 + kk * 32 + g * 8);
#pragma unroll
      for (int i = 0; i < 4; ++i)
#pragma unroll
        for (int j = 0; j < 4; ++j)
          acc[i][j] = MFMA16(af[i], bfr[j], acc[i][j]);
    }
    __syncthreads();
  }
#pragma unroll
  for (int i = 0; i < 4; ++i)
#pragma unroll
    for (int j = 0; j < 4; ++j) {
      long mrow = mBase + wr * 64 + i * 16 + g * 4;
      long ncol = nBase + wc * 64 + j * 16 + q;
      float* cp = C + mrow * N + ncol;
#pragma unroll
      for (int r = 0; r < 4; ++r) cp[(long)r * N] = acc[i][j][r];
    }
}

// ---------------- Kernel 4: split + head-RMSNorm + RoPE + gate ----------------
__global__ __launch_bounds__(256) void split_kernel(
    const float* __restrict__ qkv, const float* __restrict__ cosb,
    const float* __restrict__ sinb, const float* __restrict__ wq,
    const float* __restrict__ wk, u16* __restrict__ qb, u16* __restrict__ kb,
    float* __restrict__ gate) {
  int s = blockIdx.x;
  int w = threadIdx.x >> 6, l = threadIdx.x & 63;
  const float* row = qkv + (size_t)s * QKV_P;
  float c0 = cosb[s * HD + l],      s0 = sinb[s * HD + l];
  float c1 = cosb[s * HD + 64 + l], s1 = sinb[s * HD + 64 + l];
  const float SCALE = 0.08838834764831845f;  // 1/sqrt(128), folded into q only
  for (int h = w; h < NQh; h += 4) {
    float x0 = row[h * HD + l], x1 = row[h * HD + 64 + l];
    float ss = wave_sum64(x0 * x0 + x1 * x1);
    float n = rsqrtf(ss * (1.f / HD) + 1e-6f);
    x0 *= n * wq[l]; x1 *= n * wq[64 + l];
    qb[((size_t)s * NQh + h) * HD + l]      = f2bf((x0 * c0 - x1 * s0) * SCALE);
    qb[((size_t)s * NQh + h) * HD + 64 + l] = f2bf((x1 * c1 + x0 * s1) * SCALE);
  }
  for (int h = w; h < NKVh; h += 4) {
    float x0 = row[NQh * HD + h * HD + l], x1 = row[NQh * HD + h * HD + 64 + l];
    float ss = wave_sum64(x0 * x0 + x1 * x1);
    float n = rsqrtf(ss * (1.f / HD) + 1e-6f);
    x0 *= n * wk[l]; x1 *= n * wk[64 + l];
    kb[((size_t)h * S_LEN + s) * HD + l]      = f2bf(x0 * c0 - x1 * s0);
    kb[((size_t)h * S_LEN + s) * HD + 64 + l] = f2bf(x1 * c1 + x0 * s1);
  }
  if (threadIdx.x < NQh) {
    float gx = row[(NQh + 2 * NKVh) * HD + threadIdx.x];
    gate[(size_t)s * NQh + threadIdx.x] = 1.f / (1.f + expf(-gx));
  }
}

// ---------------- Kernel 5: flash attention v3 ----------------
// 1 wave per block, 32 q-rows; kv pipelined in 32-row half-tiles with
// register ping-pong K prefetch (kA/kB). grid (S/32, NQ).
__global__ __launch_bounds__(64, 2) void attn_kernel(
    const u16* __restrict__ qb, const u16* __restrict__ kb,
    const u16* __restrict__ vT, const float* __restrict__ gate,
    u16* __restrict__ ob) {
  int h = blockIdx.y, hk = h / 5;
  int l = threadIdx.x;
  int g = l >> 4, q = l & 15;
  int s0 = blockIdx.x * 32;
  __shared__ __align__(16) u16 Plds[2][16][40];  // wave-private [p][q][kv pad]

  bf16x8 qf[2][4];
#pragma unroll
  for (int p = 0; p < 2; ++p)
#pragma unroll
    for (int kk = 0; kk < 4; ++kk)
      qf[p][kk] = *(const bf16x8*)(qb + ((size_t)(s0 + p * 16 + q) * NQh + h) * HD + kk * 32 + g * 8);

  const u16* Kh = kb + (size_t)hk * S_LEN * HD;   // (s, d)
  const u16* Vh = vT + (size_t)hk * HD * S_LEN;   // (d, s)
  f32x4 oacc[8][2] = {};
  float m_run[2] = {-1e30f, -1e30f};
  float l_run[2] = {0.f, 0.f};
  const float L2E = 1.4426950408889634f;

  bf16x8 kA[2][4], kB[2][4];

#define LOADK(BUF, HT)                                                          \
  do {                                                                          \
    _Pragma("unroll")                                                           \
    for (int kt = 0; kt < 2; ++kt)                                              \
      _Pragma("unroll")                                                         \
      for (int kk = 0; kk < 4; ++kk)                                            \
        BUF[kt][kk] = *(const bf16x8*)(Kh + (size_t)((HT) * 32 + kt * 16 + q) * HD + kk * 32 + g * 8); \
  } while (0)

#define STEP(BUF, HT)                                                           \
  do {                                                                          \
    f32x4 sacc[2][2] = {};                                                      \
    _Pragma("unroll")                                                           \
    for (int kk = 0; kk < 4; ++kk) {                                            \
      __builtin_amdgcn_s_setprio(1);                                            \
      _Pragma("unroll")                                                         \
      for (int kt = 0; kt < 2; ++kt) {                                          \
        sacc[kt][0] = MFMA16(BUF[kt][kk], qf[0][kk], sacc[kt][0]);              \
        sacc[kt][1] = MFMA16(BUF[kt][kk], qf[1][kk], sacc[kt][1]);              \
      }                                                                         \
      __builtin_amdgcn_s_setprio(0);                                            \
    }                                                                           \
    bf16x8 va[8];                                                               \
    _Pragma("unroll")                                                           \
    for (int dt = 0; dt < 8; ++dt)                                              \
      va[dt] = *(const bf16x8*)(Vh + (size_t)(dt * 16 + q) * S_LEN + (HT) * 32 + g * 8); \
    _Pragma("unroll")                                                           \
    for (int p = 0; p < 2; ++p) {                                               \
      float mx = sacc[0][p][0];                                                 \
      _Pragma("unroll")                                                         \
      for (int kt = 0; kt < 2; ++kt)                                            \
        _Pragma("unroll")                                                       \
        for (int r = 0; r < 4; ++r)                                             \
          if (kt | r) mx = fmaxf(mx, sacc[kt][p][r]);                           \
      mx = fmaxf(mx, __shfl_xor(mx, 16, 64));                                   \
      mx = fmaxf(mx, __shfl_xor(mx, 32, 64));                                   \
      float mnew = fmaxf(m_run[p], mx);                                         \
      float rs = 0.f;                                                           \
      _Pragma("unroll")                                                         \
      for (int kt = 0; kt < 2; ++kt)                                            \
        _Pragma("unroll")                                                       \
        for (int r = 0; r < 4; ++r) {                                           \
          float pe = exp2f((sacc[kt][p][r] - mnew) * L2E);                      \
          sacc[kt][p][r] = pe;                                                  \
          rs += pe;                                                             \
        }                                                                       \
      rs += __shfl_xor(rs, 16, 64);                                             \
      rs += __shfl_xor(rs, 32, 64);                                             \
      if (__any(mx > m_run[p])) {                                               \
        float corr = exp2f((m_run[p] - mnew) * L2E);                            \
        _Pragma("unroll")                                                       \
        for (int dt = 0; dt < 8; ++dt) oacc[dt][p] *= corr;                     \
        l_run[p] *= corr;                                                       \
      }                                                                         \
      l_run[p] += rs;                                                           \
      m_run[p] = mnew;                                                          \
      _Pragma("unroll")                                                         \
      for (int kt = 0; kt < 2; ++kt) {                                          \
        u16x4 pk;                                                               \
        _Pragma("unroll")                                                       \
        for (int r = 0; r < 4; ++r) pk[r] = f2bf(sacc[kt][p][r]);               \
        *(u16x4*)&Plds[p][q][kt * 16 + g * 4] = pk;                             \
      }                                                                         \
    }                                                                           \
    bf16x8 pf0 = *(const bf16x8*)&Plds[0][q][g * 8];                            \
    bf16x8 pf1 = *(const bf16x8*)&Plds[1][q][g * 8];                            \
    __builtin_amdgcn_s_setprio(1);                                              \
    _Pragma("unroll")                                                           \
    for (int dt = 0; dt < 8; ++dt) {                                            \
      oacc[dt][0] = MFMA16(va[dt], pf0, oacc[dt][0]);                           \
      oacc[dt][1] = MFMA16(va[dt], pf1, oacc[dt][1]);                           \
    }                                                                           \
    __builtin_amdgcn_s_setprio(0);                                              \
  } while (0)

  LOADK(kA, 0);
  for (int ht = 0; ht < 64; ht += 2) {
    LOADK(kB, ht + 1);
    STEP(kA, ht);
    int htn = (ht + 2 < 64) ? ht + 2 : 63;
    LOADK(kA, htn);
    STEP(kB, ht + 1);
  }
#undef LOADK
#undef STEP

#pragma unroll
  for (int p = 0; p < 2; ++p) {
    float gt = gate[(size_t)(s0 + p * 16 + q) * NQh + h] / l_run[p];
#pragma unroll
    for (int dt = 0; dt < 8; ++dt) {
      u16x4 o;
#pragma unroll
      for (int r = 0; r < 4; ++r) o[r] = f2bf(oacc[dt][p][r] * gt);
      *(u16x4*)(ob + ((size_t)(s0 + p * 16 + q) * NQh + h) * HD + dt * 16 + g * 4) = o;
    }
  }
}

// ---------------- host ----------------
extern "C" void kernel_launch(void* const* d_in, const int* in_sizes, int n_in,
                              void* d_out, int out_size, void* d_ws, size_t ws_size,
                              hipStream_t stream) {
  const float* x     = (const float*)d_in[0];
  const float* rc    = (const float*)d_in[1];
  const float* rs    = (const float*)d_in[2];
  const float* wpre  = (const float*)d_in[3];
  const float* wqkv  = (const float*)d_in[4];
  const float* wqn   = (const float*)d_in[5];
  const float* wkn   = (const float*)d_in[6];
  const float* wproj = (const float*)d_in[7];
  float* out = (float*)d_out;

  char* ws = (char*)d_ws;
  size_t off = 0;
  auto alloc = [&](size_t bytes) -> void* {
    void* p = ws + off;
    off += (bytes + 255) & ~(size_t)255;
    return p;
  };
  u16*   xn     = (u16*)  alloc((size_t)S_LEN * HIDd * 2);
  u16*   wqkvT  = (u16*)  alloc((size_t)QKV_P * HIDd * 2);
  u16*   wprojT = (u16*)  alloc((size_t)HIDd * HIDd * 2);
  float* qkv    = (float*)alloc((size_t)S_LEN * QKV_P * 4);
  u16*   qb     = (u16*)  alloc((size_t)S_LEN * NQh * HD * 2);
  u16*   kb     = (u16*)  alloc((size_t)NKVh * S_LEN * HD * 2);
  u16*   vT     = (u16*)  alloc((size_t)NKVh * HD * S_LEN * 2);
  float* gate   = (float*)alloc((size_t)S_LEN * NQh * 4);
  u16*   ob     = (u16*)  alloc((size_t)S_LEN * NQh * HD * 2);
  if (off > ws_size) return;  // workspace insufficient -> visible clean failure

  prenorm_kernel<<<S_LEN, 256, 0, stream>>>(x, wpre, xn);
  transpose_cvt<<<dim3(QKV_P / 32, HIDd / 32, 1), 256, 0, stream>>>(
      wqkv, wqkvT, QKV_C, (long)QKV_C, (long)HIDd, 0, 0);
  transpose_cvt<<<dim3(HIDd / 32, HIDd / 32, 1), 256, 0, stream>>>(
      wproj, wprojT, HIDd, (long)HIDd, (long)HIDd, 0, 0);
  gemm_bt<<<dim3(QKV_P / 128, S_LEN / 128), 256, 0, stream>>>(
      xn, wqkvT, qkv, S_LEN, QKV_P, HIDd);
  split_kernel<<<S_LEN, 256, 0, stream>>>(qkv, rc, rs, wqn, wkn, qb, kb, gate);
  transpose_cvt<<<dim3(HD / 32, S_LEN / 32, NKVh), 256, 0, stream>>>(
      qkv + (NQh + NKVh) * HD, vT, HD, (long)QKV_P, (long)S_LEN,
      128, (long)HD * S_LEN);
  attn_kernel<<<dim3(S_LEN / 32, NQh), 64, 0, stream>>>(qb, kb, vT, gate, ob);
  gemm_bt<<<dim3(HIDd / 128, S_LEN / 128), 256, 0, stream>>>(
      ob, wprojT, out, S_LEN, HIDd, HIDd);
}

// Round 4
// 911.502 us; speedup vs baseline: 1.3968x; 1.0357x over previous
//
#include <hip/hip_runtime.h>
#include <hip/hip_bf16.h>
#include <stdint.h>

#define S_LEN 2048
#define NQh   40
#define NKVh  8
#define HD    128
#define HIDd  5120
#define QKV_C 7208
#define QKV_P 7296   // padded to multiple of 128
#define NROW  (S_LEN * NQh)   // 81920 (q-row, head) pairs

typedef unsigned short u16;
typedef short bf16x8 __attribute__((ext_vector_type(8)));
typedef float f32x4  __attribute__((ext_vector_type(4)));
typedef u16   u16x4  __attribute__((ext_vector_type(4)));

typedef const __attribute__((address_space(1))) void* gas_ptr;
typedef __attribute__((address_space(3))) void*       las_ptr;

#define MFMA16(a, b, c) __builtin_amdgcn_mfma_f32_16x16x32_bf16(a, b, c, 0, 0, 0)

__device__ __forceinline__ u16 f2bf(float f) {
  union { float f; unsigned u; } v; v.f = f;
  return (u16)((v.u + 0x7fffu + ((v.u >> 16) & 1u)) >> 16);
}
// compiler-lowered bf16 convert (fast path for attn inner loop)
__device__ __forceinline__ u16 f2bf_c(float f) {
  union { __hip_bfloat16 b; u16 u; } v;
  v.b = __float2bfloat16(f);
  return v.u;
}

__device__ __forceinline__ float wave_sum64(float x) {
#pragma unroll
  for (int m = 32; m > 0; m >>= 1) x += __shfl_xor(x, m, 64);
  return x;
}

// ---------------- Kernel 1: pre-norm RMSNorm -> bf16 ----------------
__global__ __launch_bounds__(256) void prenorm_kernel(
    const float* __restrict__ x, const float* __restrict__ w, u16* __restrict__ xn) {
  int row = blockIdx.x;
  const float4* xr = (const float4*)(x + (size_t)row * HIDd);
  const float4* wr = (const float4*)w;
  float4 vx[5];
  float ss = 0.f;
#pragma unroll
  for (int c = 0; c < 5; ++c) {
    int i = c * 256 + threadIdx.x;
    vx[c] = xr[i];
    ss += vx[c].x * vx[c].x + vx[c].y * vx[c].y + vx[c].z * vx[c].z + vx[c].w * vx[c].w;
  }
  ss = wave_sum64(ss);
  __shared__ float red[4];
  if ((threadIdx.x & 63) == 0) red[threadIdx.x >> 6] = ss;
  __syncthreads();
  float tot = red[0] + red[1] + red[2] + red[3];
  float n = rsqrtf(tot * (1.f / HIDd) + 1e-6f);
  u16x4* out = (u16x4*)(xn + (size_t)row * HIDd);
#pragma unroll
  for (int c = 0; c < 5; ++c) {
    int i = c * 256 + threadIdx.x;
    float4 vw = wr[i];
    u16x4 o;
    o.x = f2bf(vx[c].x * n * vw.x);
    o.y = f2bf(vx[c].y * n * vw.y);
    o.z = f2bf(vx[c].z * n * vw.z);
    o.w = f2bf(vx[c].w * n * vw.w);
    out[i] = o;
  }
}

// ---------------- Kernel 2: transpose + fp32->bf16 ----------------
__global__ __launch_bounds__(256) void transpose_cvt(
    const float* __restrict__ src, u16* __restrict__ dst,
    int C, long ld_src, long ld_dst, long srcZ, long dstZ) {
  src += (long)blockIdx.z * srcZ;
  dst += (long)blockIdx.z * dstZ;
  __shared__ float t[32][33];
  int tx = threadIdx.x & 31, ty = threadIdx.x >> 5;
  int c0 = blockIdx.x * 32, r0 = blockIdx.y * 32;
#pragma unroll
  for (int i = 0; i < 32; i += 8) {
    int c = c0 + tx;
    t[ty + i][tx] = (c < C) ? src[(long)(r0 + ty + i) * ld_src + c] : 0.f;
  }
  __syncthreads();
#pragma unroll
  for (int i = 0; i < 32; i += 8) {
    int c = c0 + ty + i;
    dst[(long)c * ld_dst + (r0 + tx)] = f2bf(t[tx][ty + i]);
  }
}

// ---------------- Kernel 3: GEMM  C(MxN) = A(MxK bf16) * BT(NxK bf16)^T ----------------
__global__ __launch_bounds__(256) void gemm_bt(
    const u16* __restrict__ A, const u16* __restrict__ BT, float* __restrict__ C,
    int M, int N, int K) {
  __shared__ __align__(16) u16 As[128 * 64];
  __shared__ __align__(16) u16 Bs[128 * 64];
  int w = threadIdx.x >> 6, l = threadIdx.x & 63;
  int wr = w >> 1, wc = w & 1;
  int g = l >> 4, q = l & 15;
  int nwg = gridDim.x * gridDim.y;
  int wgid = blockIdx.y * gridDim.x + blockIdx.x;
  int swz = (wgid & 7) * (nwg >> 3) + (wgid >> 3);
  int bx = swz % gridDim.x, by = swz / gridDim.x;
  long mBase = (long)by * 128;
  long nBase = (long)bx * 128;
  const u16* aTile = A + mBase * K;
  const u16* bTile = BT + nBase * K;
  f32x4 acc[4][4] = {};

  for (int k0 = 0; k0 < K; k0 += 64) {
#pragma unroll
    for (int i = 0; i < 4; ++i) {
      int s = (w * 4 + i) * 64 + l;
      int row = s >> 3, seg = s & 7;
      __builtin_amdgcn_global_load_lds(
          (gas_ptr)(aTile + (long)row * K + k0 + seg * 8),
          (las_ptr)(As + (w * 4 + i) * 512), 16, 0, 0);
      __builtin_amdgcn_global_load_lds(
          (gas_ptr)(bTile + (long)row * K + k0 + seg * 8),
          (las_ptr)(Bs + (w * 4 + i) * 512), 16, 0, 0);
    }
    __syncthreads();
#pragma unroll
    for (int kk = 0; kk < 2; ++kk) {
      bf16x8 af[4], bfr[4];
#pragma unroll
      for (int i = 0; i < 4; ++i)
        af[i] = *(const bf16x8*)(As + (wr * 64 + i * 16 + q) * 64 + kk * 32 + g * 8);
#pragma unroll
      for (int j = 0; j < 4; ++j)
        bfr[j] = *(const bf16x8*)(Bs + (wc * 64 + j * 16 + q) * 64 + kk * 32 + g * 8);
#pragma unroll
      for (int i = 0; i < 4; ++i)
#pragma unroll
        for (int j = 0; j < 4; ++j)
          acc[i][j] = MFMA16(af[i], bfr[j], acc[i][j]);
    }
    __syncthreads();
  }
#pragma unroll
  for (int i = 0; i < 4; ++i)
#pragma unroll
    for (int j = 0; j < 4; ++j) {
      long mrow = mBase + wr * 64 + i * 16 + g * 4;
      long ncol = nBase + wc * 64 + j * 16 + q;
      float* cp = C + mrow * N + ncol;
#pragma unroll
      for (int r = 0; r < 4; ++r) cp[(long)r * N] = acc[i][j][r];
    }
}

// ---------------- Kernel 4: split + head-RMSNorm + RoPE + gate ----------------
// Q is scaled by (1/sqrt(D)) * log2(e): attention scores come out in log2 domain.
__global__ __launch_bounds__(256) void split_kernel(
    const float* __restrict__ qkv, const float* __restrict__ cosb,
    const float* __restrict__ sinb, const float* __restrict__ wq,
    const float* __restrict__ wk, u16* __restrict__ qb, u16* __restrict__ kb,
    float* __restrict__ gate) {
  int s = blockIdx.x;
  int w = threadIdx.x >> 6, l = threadIdx.x & 63;
  const float* row = qkv + (size_t)s * QKV_P;
  float c0 = cosb[s * HD + l],      s0 = sinb[s * HD + l];
  float c1 = cosb[s * HD + 64 + l], s1 = sinb[s * HD + 64 + l];
  const float SCALE = 0.12751743f;  // (1/sqrt(128)) * log2(e)
  for (int h = w; h < NQh; h += 4) {
    float x0 = row[h * HD + l], x1 = row[h * HD + 64 + l];
    float ss = wave_sum64(x0 * x0 + x1 * x1);
    float n = rsqrtf(ss * (1.f / HD) + 1e-6f);
    x0 *= n * wq[l]; x1 *= n * wq[64 + l];
    qb[((size_t)s * NQh + h) * HD + l]      = f2bf((x0 * c0 - x1 * s0) * SCALE);
    qb[((size_t)s * NQh + h) * HD + 64 + l] = f2bf((x1 * c1 + x0 * s1) * SCALE);
  }
  for (int h = w; h < NKVh; h += 4) {
    float x0 = row[NQh * HD + h * HD + l], x1 = row[NQh * HD + h * HD + 64 + l];
    float ss = wave_sum64(x0 * x0 + x1 * x1);
    float n = rsqrtf(ss * (1.f / HD) + 1e-6f);
    x0 *= n * wk[l]; x1 *= n * wk[64 + l];
    kb[((size_t)h * S_LEN + s) * HD + l]      = f2bf(x0 * c0 - x1 * s0);
    kb[((size_t)h * S_LEN + s) * HD + 64 + l] = f2bf(x1 * c1 + x0 * s1);
  }
  if (threadIdx.x < NQh) {
    float gx = row[(NQh + 2 * NKVh) * HD + threadIdx.x];
    gate[(size_t)s * NQh + threadIdx.x] = 1.f / (1.f + expf(-gx));
  }
}

// ---------------- Kernel 5: flash attention v4 (kv-split partials) ----------------
// grid (S/32, NQ, 2); 1 wave, 32 q-rows, kv range [z*1024, z*1024+1024).
// Writes unnormalized O~ (f32), m (log2-domain), l partials.
__global__ __launch_bounds__(64, 2) void attn_kernel(
    const u16* __restrict__ qb, const u16* __restrict__ kb,
    const u16* __restrict__ vT,
    float* __restrict__ opart, float* __restrict__ mpart, float* __restrict__ lpart) {
  int h = blockIdx.y, hk = h / 5;
  int z = blockIdx.z;
  int l = threadIdx.x;
  int g = l >> 4, q = l & 15;
  int s0 = blockIdx.x * 32;
  __shared__ __align__(16) u16 Plds[2][16][40];

  bf16x8 qf[2][4];
#pragma unroll
  for (int p = 0; p < 2; ++p)
#pragma unroll
    for (int kk = 0; kk < 4; ++kk)
      qf[p][kk] = *(const bf16x8*)(qb + ((size_t)(s0 + p * 16 + q) * NQh + h) * HD + kk * 32 + g * 8);

  const u16* Kh = kb + ((size_t)hk * S_LEN + z * 1024) * HD;  // (s, d)
  const u16* Vh = vT + (size_t)hk * HD * S_LEN + z * 1024;    // (d, s)
  f32x4 oacc[8][2] = {};
  float m_run[2] = {-1e30f, -1e30f};
  float l_run[2] = {0.f, 0.f};

  bf16x8 kA[2][4], kB[2][4];

#define LOADK(BUF, HT)                                                          \
  do {                                                                          \
    _Pragma("unroll")                                                           \
    for (int kt = 0; kt < 2; ++kt)                                              \
      _Pragma("unroll")                                                         \
      for (int kk = 0; kk < 4; ++kk)                                            \
        BUF[kt][kk] = *(const bf16x8*)(Kh + (size_t)((HT) * 32 + kt * 16 + q) * HD + kk * 32 + g * 8); \
  } while (0)

#define STEP(BUF, HT)                                                           \
  do {                                                                          \
    f32x4 sacc[2][2] = {};                                                      \
    _Pragma("unroll")                                                           \
    for (int kk = 0; kk < 4; ++kk) {                                            \
      __builtin_amdgcn_s_setprio(1);                                            \
      _Pragma("unroll")                                                         \
      for (int kt = 0; kt < 2; ++kt) {                                          \
        sacc[kt][0] = MFMA16(BUF[kt][kk], qf[0][kk], sacc[kt][0]);              \
        sacc[kt][1] = MFMA16(BUF[kt][kk], qf[1][kk], sacc[kt][1]);              \
      }                                                                         \
      __builtin_amdgcn_s_setprio(0);                                            \
    }                                                                           \
    bf16x8 va[8];                                                               \
    _Pragma("unroll")                                                           \
    for (int dt = 0; dt < 8; ++dt)                                              \
      va[dt] = *(const bf16x8*)(Vh + (size_t)(dt * 16 + q) * S_LEN + (HT) * 32 + g * 8); \
    _Pragma("unroll")                                                           \
    for (int p = 0; p < 2; ++p) {                                               \
      float mx = fmaxf(fmaxf(sacc[0][p][0], sacc[0][p][1]),                     \
                       fmaxf(sacc[0][p][2], sacc[0][p][3]));                    \
      mx = fmaxf(mx, fmaxf(fmaxf(sacc[1][p][0], sacc[1][p][1]),                 \
                           fmaxf(sacc[1][p][2], sacc[1][p][3])));               \
      mx = fmaxf(mx, __shfl_xor(mx, 16, 64));                                   \
      mx = fmaxf(mx, __shfl_xor(mx, 32, 64));                                   \
      float mnew = fmaxf(m_run[p], mx);                                         \
      float rs = 0.f;                                                           \
      _Pragma("unroll")                                                         \
      for (int kt = 0; kt < 2; ++kt)                                            \
        _Pragma("unroll")                                                       \
        for (int r = 0; r < 4; ++r) {                                           \
          float pe = exp2f(sacc[kt][p][r] - mnew);                              \
          sacc[kt][p][r] = pe;                                                  \
          rs += pe;                                                             \
        }                                                                       \
      rs += __shfl_xor(rs, 16, 64);                                             \
      rs += __shfl_xor(rs, 32, 64);                                             \
      if (__any(mx > m_run[p])) {                                               \
        float corr = exp2f(m_run[p] - mnew);                                    \
        _Pragma("unroll")                                                       \
        for (int dt = 0; dt < 8; ++dt) oacc[dt][p] *= corr;                     \
        l_run[p] *= corr;                                                       \
      }                                                                         \
      l_run[p] += rs;                                                           \
      m_run[p] = mnew;                                                          \
      _Pragma("unroll")                                                         \
      for (int kt = 0; kt < 2; ++kt) {                                          \
        u16x4 pk;                                                               \
        _Pragma("unroll")                                                       \
        for (int r = 0; r < 4; ++r) pk[r] = f2bf_c(sacc[kt][p][r]);             \
        *(u16x4*)&Plds[p][q][kt * 16 + g * 4] = pk;                             \
      }                                                                         \
    }                                                                           \
    bf16x8 pf0 = *(const bf16x8*)&Plds[0][q][g * 8];                            \
    bf16x8 pf1 = *(const bf16x8*)&Plds[1][q][g * 8];                            \
    __builtin_amdgcn_s_setprio(1);                                              \
    _Pragma("unroll")                                                           \
    for (int dt = 0; dt < 8; ++dt) {                                            \
      oacc[dt][0] = MFMA16(va[dt], pf0, oacc[dt][0]);                           \
      oacc[dt][1] = MFMA16(va[dt], pf1, oacc[dt][1]);                           \
    }                                                                           \
    __builtin_amdgcn_s_setprio(0);                                              \
  } while (0)

  LOADK(kA, 0);
  for (int ht = 0; ht < 32; ht += 2) {
    LOADK(kB, ht + 1);
    STEP(kA, ht);
    int htn = (ht + 2 < 32) ? ht + 2 : 31;
    LOADK(kA, htn);
    STEP(kB, ht + 1);
  }
#undef LOADK
#undef STEP

#pragma unroll
  for (int p = 0; p < 2; ++p) {
    size_t row = (size_t)(s0 + p * 16 + q) * NQh + h;
    if (g == 0) {
      mpart[(size_t)z * NROW + row] = m_run[p];
      lpart[(size_t)z * NROW + row] = l_run[p];
    }
    float* op = opart + ((size_t)z * NROW + row) * HD;
#pragma unroll
    for (int dt = 0; dt < 8; ++dt)
      *(f32x4*)(op + dt * 16 + g * 4) = oacc[dt][p];
  }
}

// ---------------- Kernel 6: combine kv-split partials + gate ----------------
// thread t: row = t/32, d = (t%32)*4. grid NROW*32/256.
__global__ __launch_bounds__(256) void combine_kernel(
    const float* __restrict__ opart, const float* __restrict__ mpart,
    const float* __restrict__ lpart, const float* __restrict__ gate,
    u16* __restrict__ ob) {
  int t = blockIdx.x * 256 + threadIdx.x;
  int row = t >> 5, dv = (t & 31) * 4;
  float m0 = mpart[row], m1 = mpart[NROW + row];
  float l0 = lpart[row], l1 = lpart[NROW + row];
  float m = fmaxf(m0, m1);
  float w0 = exp2f(m0 - m), w1 = exp2f(m1 - m);
  float sc = gate[row] / (w0 * l0 + w1 * l1);
  w0 *= sc; w1 *= sc;
  f32x4 o0 = *(const f32x4*)(opart + (size_t)row * HD + dv);
  f32x4 o1 = *(const f32x4*)(opart + (size_t)NROW * HD + (size_t)row * HD + dv);
  u16x4 o;
#pragma unroll
  for (int r = 0; r < 4; ++r) o[r] = f2bf(w0 * o0[r] + w1 * o1[r]);
  *(u16x4*)(ob + (size_t)row * HD + dv) = o;
}

// ---------------- host ----------------
extern "C" void kernel_launch(void* const* d_in, const int* in_sizes, int n_in,
                              void* d_out, int out_size, void* d_ws, size_t ws_size,
                              hipStream_t stream) {
  const float* x     = (const float*)d_in[0];
  const float* rc    = (const float*)d_in[1];
  const float* rs    = (const float*)d_in[2];
  const float* wpre  = (const float*)d_in[3];
  const float* wqkv  = (const float*)d_in[4];
  const float* wqn   = (const float*)d_in[5];
  const float* wkn   = (const float*)d_in[6];
  const float* wproj = (const float*)d_in[7];
  float* out = (float*)d_out;

  char* ws = (char*)d_ws;
  size_t off = 0;
  auto alloc = [&](size_t bytes) -> void* {
    void* p = ws + off;
    off += (bytes + 255) & ~(size_t)255;
    return p;
  };
  u16*   xn     = (u16*)  alloc((size_t)S_LEN * HIDd * 2);        // dead after QKV GEMM
  u16*   wqkvT  = (u16*)  alloc((size_t)QKV_P * HIDd * 2);        // dead after QKV GEMM
  u16*   wprojT = (u16*)  alloc((size_t)HIDd * HIDd * 2);
  float* qkv    = (float*)alloc((size_t)S_LEN * QKV_P * 4);
  u16*   qb     = (u16*)  alloc((size_t)S_LEN * NQh * HD * 2);
  u16*   kb     = (u16*)  alloc((size_t)NKVh * S_LEN * HD * 2);
  u16*   vT     = (u16*)  alloc((size_t)NKVh * HD * S_LEN * 2);
  float* gate   = (float*)alloc((size_t)S_LEN * NQh * 4);
  u16*   ob     = (u16*)  alloc((size_t)S_LEN * NQh * HD * 2);
  if (off > ws_size) return;

  // attn partials overlap the dead xn+wqkvT region (needs ~86.6MB < 95.6MB).
  float* opart = (float*)ws;                                   // 2*NROW*HD f32 = 83.9MB
  float* mpart = opart + (size_t)2 * NROW * HD;                // 2*NROW f32
  float* lpart = mpart + (size_t)2 * NROW;                     // 2*NROW f32

  prenorm_kernel<<<S_LEN, 256, 0, stream>>>(x, wpre, xn);
  transpose_cvt<<<dim3(QKV_P / 32, HIDd / 32, 1), 256, 0, stream>>>(
      wqkv, wqkvT, QKV_C, (long)QKV_C, (long)HIDd, 0, 0);
  transpose_cvt<<<dim3(HIDd / 32, HIDd / 32, 1), 256, 0, stream>>>(
      wproj, wprojT, HIDd, (long)HIDd, (long)HIDd, 0, 0);
  gemm_bt<<<dim3(QKV_P / 128, S_LEN / 128), 256, 0, stream>>>(
      xn, wqkvT, qkv, S_LEN, QKV_P, HIDd);
  split_kernel<<<S_LEN, 256, 0, stream>>>(qkv, rc, rs, wqn, wkn, qb, kb, gate);
  transpose_cvt<<<dim3(HD / 32, S_LEN / 32, NKVh), 256, 0, stream>>>(
      qkv + (NQh + NKVh) * HD, vT, HD, (long)QKV_P, (long)S_LEN,
      128, (long)HD * S_LEN);
  attn_kernel<<<dim3(S_LEN / 32, NQh, 2), 64, 0, stream>>>(
      qb, kb, vT, opart, mpart, lpart);
  combine_kernel<<<NROW * 32 / 256, 256, 0, stream>>>(
      opart, mpart, lpart, gate, ob);
  gemm_bt<<<dim3(HIDd / 128, S_LEN / 128), 256, 0, stream>>>(
      ob, wprojT, out, S_LEN, HIDd, HIDd);
}